// Round 2
// baseline (222.456 us; speedup 1.0000x reference)
//
#include <hip/hip_runtime.h>

// Problem constants
#define BSEQ 64
#define LSEQ 512
#define CCH  1024
#define NT   7            // NUM_TAGS
#define NTOK (BSEQ*LSEQ)  // 32768
#define START_TAG 5
#define STOP_TAG  6
#define NEGV (-10000.0f)

// ---------------- DPP wave64 sum (result lands in lane 63) ----------------
template<int CTRL, int RMASK, int BMASK>
__device__ __forceinline__ float dpp_add(float x) {
    int y = __builtin_amdgcn_update_dpp(0, __float_as_int(x), CTRL, RMASK, BMASK, true);
    return x + __int_as_float(y);
}
__device__ __forceinline__ float wave_sum(float x) {
    x = dpp_add<0x111, 0xF, 0xF>(x);  // row_shr:1
    x = dpp_add<0x112, 0xF, 0xF>(x);  // row_shr:2
    x = dpp_add<0x114, 0xF, 0xF>(x);  // row_shr:4
    x = dpp_add<0x118, 0xF, 0xF>(x);  // row_shr:8  -> lane15 of each row16 has row sum
    x = dpp_add<0x142, 0xA, 0xF>(x);  // row_bcast:15 into rows 1,3
    x = dpp_add<0x143, 0xC, 0xF>(x);  // row_bcast:31 into rows 2,3 -> lane63 = total
    return x;
}

// ---------------- Kernel 1: logits (X @ W^T + b), labels copy, score zero ----------------
__global__ __launch_bounds__(256)
void k_logits(const float* __restrict__ X, const float* __restrict__ W,
              const float* __restrict__ bvec, const int* __restrict__ lab,
              float* __restrict__ out)
{
    __shared__ float Wl[NT][CCH];   // 28 KB
    __shared__ float bl[NT];
    {
        const float4* W4  = (const float4*)W;
        float4*       Wl4 = (float4*)(&Wl[0][0]);
        for (int i = threadIdx.x; i < NT*CCH/4; i += 256) Wl4[i] = W4[i];
        if (threadIdx.x < NT) bl[threadIdx.x] = bvec[threadIdx.x];
    }
    __syncthreads();

    const int lane = threadIdx.x & 63;
    const int wid  = (blockIdx.x * 256 + threadIdx.x) >> 6;
    const int nw   = (gridDim.x * 256) >> 6;
    float* outP = out + 1 + NTOK;

    for (int base = wid * 4; base < NTOK; base += nw * 4) {
        // load 4 rows x 4 float4 per lane (coalesced 16B/lane)
        float4 xv[4][4];
        #pragma unroll
        for (int r = 0; r < 4; r++) {
            const float4* xr = (const float4*)(X + (size_t)(base + r) * CCH);
            #pragma unroll
            for (int k = 0; k < 4; k++) xv[k][r] = xr[k*64 + lane];
        }
        float acc[4][NT];
        #pragma unroll
        for (int r = 0; r < 4; r++)
            #pragma unroll
            for (int t = 0; t < NT; t++) acc[r][t] = 0.0f;

        #pragma unroll
        for (int k = 0; k < 4; k++) {
            const int cb = (k*64 + lane) * 4;
            #pragma unroll
            for (int t = 0; t < NT; t++) {
                const float4 wv = *(const float4*)(&Wl[t][cb]);   // unit-stride b128, conflict-free
                #pragma unroll
                for (int r = 0; r < 4; r++) {
                    acc[r][t] = fmaf(xv[k][r].x, wv.x,
                                fmaf(xv[k][r].y, wv.y,
                                fmaf(xv[k][r].z, wv.z,
                                fmaf(xv[k][r].w, wv.w, acc[r][t]))));
                }
            }
        }
        #pragma unroll
        for (int r = 0; r < 4; r++) {
            #pragma unroll
            for (int t = 0; t < NT; t++) {
                float s = wave_sum(acc[r][t]);
                if (lane == 63) outP[(size_t)(base + r) * NT + t] = s + bl[t];
            }
        }
    }

    // labels as float + zero the score slot
    for (int i = blockIdx.x * 256 + threadIdx.x; i < NTOK; i += gridDim.x * 256)
        out[1 + i] = (float)lab[i];
    if (blockIdx.x == 0 && threadIdx.x == 0) out[0] = 0.0f;
}

// ---------------- Kernel 2: CRF NLL via chunked log-semiring scan ----------------
// One block per sequence. 448 threads = 64 chunks x 7 basis vectors.
// Chunk = 8 steps computed sequentially in-registers; 7x7 chunk matrices
// tree-combined in LDS (6 levels of log-semiring matmul).
__global__ __launch_bounds__(448)
void k_crf(const float* __restrict__ dout_ro, const int* __restrict__ lab,
           const float* __restrict__ trans, float* __restrict__ score)
{
    __shared__ float E[LSEQ*NT];   // 3584 floats; reused as matrix buffer A after recurrence
    __shared__ float M2[32*49];    // ping-pong buffer B
    __shared__ float T[49];
    __shared__ float gred[7];

    const int b   = blockIdx.x;
    const int tid = threadIdx.x;
    const float* feats = dout_ro + 1 + NTOK + (size_t)b * (LSEQ*NT);

    for (int i = tid; i < LSEQ*NT; i += 448) E[i] = feats[i];  // scalar: base not 16B-aligned
    if (tid < 49) T[tid] = trans[tid];
    __syncthreads();

    // ---- gold score (parallel over tokens) ----
    float g = 0.0f;
    for (int l = tid; l < LSEQ; l += 448) {
        const int t  = lab[b*LSEQ + l];
        const int tp = (l == 0) ? START_TAG : lab[b*LSEQ + l - 1];
        g += E[l*NT + t] + T[t*NT + tp];
    }
    if (tid == 0) g += T[STOP_TAG*NT + lab[b*LSEQ + LSEQ - 1]];
    {
        float gs = wave_sum(g);
        if ((tid & 63) == 63) gred[tid >> 6] = gs;
    }

    // ---- chunk basis recurrences (all in registers) ----
    float TR[49];
    #pragma unroll
    for (int i = 0; i < 49; i++) TR[i] = T[i];

    const int chunk = tid / 7;
    const int basis = tid - chunk * 7;
    float fv[7];
    #pragma unroll
    for (int j = 0; j < 7; j++) fv[j] = (j == basis) ? 0.0f : NEGV;

    const int l0 = chunk * 8;
    for (int s = 0; s < 8; s++) {
        float e[7];
        #pragma unroll
        for (int j = 0; j < 7; j++) e[j] = E[(l0 + s)*NT + j];
        float fn[7];
        #pragma unroll
        for (int j = 0; j < 7; j++) {
            float v[7];
            #pragma unroll
            for (int k = 0; k < 7; k++) v[k] = fv[k] + TR[j*7 + k];
            float m = fmaxf(fmaxf(fmaxf(v[0], v[1]), fmaxf(v[2], v[3])),
                            fmaxf(fmaxf(v[4], v[5]), v[6]));
            float sum = 0.0f;
            #pragma unroll
            for (int k = 0; k < 7; k++) sum += __expf(v[k] - m);
            fn[j] = m + __logf(sum) + e[j];
        }
        #pragma unroll
        for (int j = 0; j < 7; j++) fv[j] = fn[j];
    }
    __syncthreads();   // all E reads done; safe to overwrite with matrices
    #pragma unroll
    for (int j = 0; j < 7; j++) E[chunk*49 + basis*7 + j] = fv[j];

    // ---- tree combine: C[i][j] = lse_k(A[i][k] + B[k][j]) ----
    // NOTE: no LDS-pointer arrays (addrspacecast static-init is rejected on
    // gfx950) — select buffers with a ternary each level instead.
    int n = 64, cur = 0;
    while (n > 1) {
        __syncthreads();
        const float* in = (cur == 0) ? (const float*)E : (const float*)M2;
        float*       ob = (cur == 0) ? M2 : E;
        const int half = n >> 1;
        for (int e2 = tid; e2 < half*49; e2 += 448) {
            const int p = e2 / 49, r = e2 - p*49;
            const int i = r / 7,  j = r - (r/7)*7;
            const float* A  = in + (2*p)*49 + i*7;
            const float* Bm = in + (2*p + 1)*49 + j;
            float v[7];
            #pragma unroll
            for (int k = 0; k < 7; k++) v[k] = A[k] + Bm[k*7];
            float m = fmaxf(fmaxf(fmaxf(v[0], v[1]), fmaxf(v[2], v[3])),
                            fmaxf(fmaxf(v[4], v[5]), v[6]));
            float sum = 0.0f;
            #pragma unroll
            for (int k = 0; k < 7; k++) sum += __expf(v[k] - m);
            ob[p*49 + r] = m + __logf(sum);
        }
        cur ^= 1; n = half;
    }
    __syncthreads();

    if (tid == 0) {
        float gg = 0.0f;
        #pragma unroll
        for (int w = 0; w < 7; w++) gg += gred[w];
        const float* M = (cur == 0) ? (const float*)E : (const float*)M2;  // final 7x7 total matrix
        float v[7];
        #pragma unroll
        for (int j = 0; j < 7; j++) v[j] = M[START_TAG*7 + j] + T[STOP_TAG*7 + j];
        float m = fmaxf(fmaxf(fmaxf(v[0], v[1]), fmaxf(v[2], v[3])),
                        fmaxf(fmaxf(v[4], v[5]), v[6]));
        float sum = 0.0f;
        #pragma unroll
        for (int j = 0; j < 7; j++) sum += __expf(v[j] - m);
        float fwd = m + __logf(sum);
        atomicAdd(score, fwd - gg);
    }
}

extern "C" void kernel_launch(void* const* d_in, const int* in_sizes, int n_in,
                              void* d_out, int out_size, void* d_ws, size_t ws_size,
                              hipStream_t stream) {
    const float* X     = (const float*)d_in[0];   // fuse_embeddings [32768,1024]
    const int*   lab   = (const int*)  d_in[1];   // label_class [32768]
    const float* W     = (const float*)d_in[2];   // [7,1024]
    const float* bvec  = (const float*)d_in[3];   // [7]
    const float* trans = (const float*)d_in[4];   // [7,7]
    float* out = (float*)d_out;

    k_logits<<<512, 256, 0, stream>>>(X, W, bvec, lab, out);
    k_crf<<<BSEQ, 448, 0, stream>>>(out, lab, trans, out);
}